// Round 1
// baseline (1164.496 us; speedup 1.0000x reference)
//
#include <hip/hip_runtime.h>
#include <math.h>

#define BATCH     512
#define T_PAST_   360
#define T_FUT_    1800
#define IN_SZ     3
#define H_SZ      64
#define FUT_SEQ   50
#define WSPF_     34
#define MAX_STEPS (FUT_SEQ * WSPF_)      // 1700
#define T_TOT     (T_PAST_ + MAX_STEPS)  // 2060
#define NGATES    (4 * H_SZ)             // 256

__device__ __forceinline__ float sigmoid_(float x) {
    // 1/(1+exp(-x)); exp(-x) may overflow to +inf for very negative x -> 1/inf = 0, OK.
    return 1.0f / (1.0f + __expf(-x));
}

__device__ __forceinline__ float tanh_(float x) {
    // tanh via exp of the NEGATIVE magnitude only (no overflow), sign restored.
    float a = fabsf(x);
    float e = __expf(-2.0f * a);         // in (0,1]
    float t = (1.0f - e) / (1.0f + e);
    return copysignf(t, x);
}

__global__ __launch_bounds__(NGATES, 2)
void lstm_fused_kernel(const float* __restrict__ wave_input,   // [B, 360, 3]
                       const float* __restrict__ wave_future,  // [B, 1800, 3]
                       const float* __restrict__ W_ih,         // [256, 3]
                       const float* __restrict__ W_hh,         // [256, 64]
                       const float* __restrict__ b_ih,         // [256]
                       const float* __restrict__ b_hh,         // [256]
                       const float* __restrict__ W_proj,       // [64, 64]
                       const float* __restrict__ b_proj,       // [64]
                       float* __restrict__ out)                // [B, 50, 64]
{
    __shared__ __align__(16) float x_lds[T_TOT * IN_SZ];   // 6180 floats = 24.7 KB
    __shared__ __align__(16) float wproj_lds[H_SZ * 65];   // padded rows, 16.6 KB
    __shared__ __align__(16) float gates_lds[NGATES];      // 1 KB
    __shared__ __align__(16) float h_lds[H_SZ];            // 256 B
    __shared__ __align__(16) float bproj_lds[H_SZ];        // 256 B

    const int b   = blockIdx.x;
    const int tid = threadIdx.x;

    // ---- stage this batch element's input sequence into LDS (coalesced) ----
    {
        const float* wi = wave_input + (size_t)b * (T_PAST_ * IN_SZ);
        for (int i = tid; i < T_PAST_ * IN_SZ; i += NGATES) x_lds[i] = wi[i];
        const float* wf = wave_future + (size_t)b * (T_FUT_ * IN_SZ);
        for (int i = tid; i < MAX_STEPS * IN_SZ; i += NGATES)
            x_lds[T_PAST_ * IN_SZ + i] = wf[i];
    }
    // ---- W_proj into LDS, padded stride 65 -> bank (j+m)%32, conflict-free ----
    for (int i = tid; i < H_SZ * H_SZ; i += NGATES) {
        int r = i >> 6, cc = i & 63;
        wproj_lds[r * 65 + cc] = W_proj[i];
    }
    if (tid < H_SZ) {
        bproj_lds[tid] = b_proj[tid];
        h_lds[tid]     = 0.0f;
    }

    // ---- per-thread recurrent weights: row g of W_hh in 64 VGPRs ----
    float whh[H_SZ];
    {
        const float4* row = (const float4*)(W_hh + tid * H_SZ);
        #pragma unroll
        for (int j = 0; j < 16; ++j) {
            float4 v = row[j];
            whh[4 * j + 0] = v.x; whh[4 * j + 1] = v.y;
            whh[4 * j + 2] = v.z; whh[4 * j + 3] = v.w;
        }
    }
    const float wih0 = W_ih[tid * 3 + 0];
    const float wih1 = W_ih[tid * 3 + 1];
    const float wih2 = W_ih[tid * 3 + 2];
    const float bg   = b_ih[tid] + b_hh[tid];
    const bool  gate_is_tanh = (tid >= 2 * H_SZ) && (tid < 3 * H_SZ);  // g-gate

    float c = 0.0f;                       // cell state, lanes 0..63 of wave 0
    float* outb = out + (size_t)b * (FUT_SEQ * H_SZ);
    int next_cp = T_PAST_ + WSPF_ - 1;    // first checkpoint t = 393
    int cp_k = 0;

    __syncthreads();

    for (int t = 0; t < T_TOT; ++t) {
        // gate pre-activation: bias + W_ih·x_t + W_hh·h  (h broadcast from LDS)
        float x0 = x_lds[t * 3 + 0];
        float x1 = x_lds[t * 3 + 1];
        float x2 = x_lds[t * 3 + 2];
        float acc = fmaf(wih0, x0, fmaf(wih1, x1, fmaf(wih2, x2, bg)));

        const float4* h4 = (const float4*)h_lds;
        #pragma unroll
        for (int j = 0; j < 16; ++j) {
            float4 hv = h4[j];
            acc = fmaf(whh[4 * j + 0], hv.x, acc);
            acc = fmaf(whh[4 * j + 1], hv.y, acc);
            acc = fmaf(whh[4 * j + 2], hv.z, acc);
            acc = fmaf(whh[4 * j + 3], hv.w, acc);
        }

        gates_lds[tid] = gate_is_tanh ? tanh_(acc) : sigmoid_(acc);
        __syncthreads();   // B1: gates visible; everyone done reading old h_lds

        if (tid < H_SZ) {
            float gi = gates_lds[tid];
            float gf = gates_lds[H_SZ + tid];
            float gg = gates_lds[2 * H_SZ + tid];
            float go = gates_lds[3 * H_SZ + tid];
            c = fmaf(gf, c, gi * gg);
            float h = go * tanh_(c);
            h_lds[tid] = h;

            if (t == next_cp) {           // wave-0-uniform branch
                // out[b, k, j] = b_proj[j] + sum_m W_proj[j,m] * h[m]
                float p = bproj_lds[tid];
                #pragma unroll 8
                for (int m = 0; m < H_SZ; ++m)
                    p = fmaf(wproj_lds[tid * 65 + m], h_lds[m], p);
                outb[cp_k * H_SZ + tid] = p;
                next_cp += WSPF_;
                ++cp_k;
            }
        }
        __syncthreads();   // B2: new h visible for next step
    }
}

extern "C" void kernel_launch(void* const* d_in, const int* in_sizes, int n_in,
                              void* d_out, int out_size, void* d_ws, size_t ws_size,
                              hipStream_t stream) {
    const float* wave_input  = (const float*)d_in[0];
    const float* wave_future = (const float*)d_in[1];
    const float* W_ih        = (const float*)d_in[2];
    const float* W_hh        = (const float*)d_in[3];
    const float* b_ih        = (const float*)d_in[4];
    const float* b_hh        = (const float*)d_in[5];
    const float* W_proj      = (const float*)d_in[6];
    const float* b_proj      = (const float*)d_in[7];
    float* out               = (float*)d_out;

    lstm_fused_kernel<<<BATCH, NGATES, 0, stream>>>(
        wave_input, wave_future, W_ih, W_hh, b_ih, b_hh, W_proj, b_proj, out);
}